// Round 1
// baseline (251.651 us; speedup 1.0000x reference)
//
#include <hip/hip_runtime.h>
#include <hip/hip_bf16.h>

// Problem constants
#define DM    1024
#define NH    16
#define DKH   64
#define BB    2
#define SS    2048
#define MROWS (BB*SS)   // 4096

typedef __attribute__((ext_vector_type(8))) short s16x8;
typedef __attribute__((ext_vector_type(4))) float f32x4;
typedef unsigned short u16;

__device__ inline u16 f2b(float f) {
    __hip_bfloat16 h = __float2bfloat16(f);
    return __builtin_bit_cast(u16, h);
}
__device__ inline float b2f(u16 u) {
    return __bfloat162float(__builtin_bit_cast(__hip_bfloat16, u));
}

__device__ inline f32x4 mfma16(s16x8 a, s16x8 b, f32x4 c) {
    return __builtin_amdgcn_mfma_f32_16x16x32_bf16(a, b, c, 0, 0, 0);
}

__device__ inline void gload_lds16(const u16* g, u16* l) {
    __builtin_amdgcn_global_load_lds((const __attribute__((address_space(1))) void*)g,
                                     (__attribute__((address_space(3))) void*)l, 16, 0, 0);
}

// ---------------- prep: fp32 -> bf16 casts ----------------
__global__ void k_prep(const float* __restrict__ x, const float* __restrict__ wq,
                       const float* __restrict__ wk, const float* __restrict__ wv,
                       const float* __restrict__ wo,
                       u16* __restrict__ xb, u16* __restrict__ wqkvb, u16* __restrict__ wob) {
    int64_t i0 = (int64_t)blockIdx.x * blockDim.x + threadIdx.x;
    int64_t strd = (int64_t)gridDim.x * blockDim.x;
    const float4* x4 = (const float4*)x;
    ushort4* xb4 = (ushort4*)xb;
    for (int64_t t = i0; t < (int64_t)MROWS*DM/4; t += strd) {
        float4 v = x4[t];
        xb4[t] = make_ushort4(f2b(v.x), f2b(v.y), f2b(v.z), f2b(v.w));
    }
    const float4* q4 = (const float4*)wq;
    const float4* k4 = (const float4*)wk;
    const float4* v4 = (const float4*)wv;
    const float4* o4 = (const float4*)wo;
    ushort4* w4  = (ushort4*)wqkvb;
    ushort4* wo4 = (ushort4*)wob;
    const int64_t nw4 = (int64_t)DM*DM/4;   // 262144
    for (int64_t t = i0; t < nw4; t += strd) {
        float4 a = q4[t]; w4[t]         = make_ushort4(f2b(a.x), f2b(a.y), f2b(a.z), f2b(a.w));
        float4 b = k4[t]; w4[nw4 + t]   = make_ushort4(f2b(b.x), f2b(b.y), f2b(b.z), f2b(b.w));
        float4 c = v4[t]; w4[2*nw4 + t] = make_ushort4(f2b(c.x), f2b(c.y), f2b(c.z), f2b(c.w));
        float4 d = o4[t]; wo4[t]        = make_ushort4(f2b(d.x), f2b(d.y), f2b(d.z), f2b(d.w));
    }
}

// ---------------- RoPE cos/sin table ----------------
__global__ void k_rope_table(const int* __restrict__ pos, float2* __restrict__ tab) {
    int i = blockIdx.x * blockDim.x + threadIdx.x;  // SS*32 = 65536
    if (i >= SS * 32) return;
    int s = i >> 5, j = i & 31;
    float p = (float)pos[s];
    float freq = powf(10000.0f, -(float)(2 * j) * (1.0f / 64.0f));
    float a = p * freq;
    tab[i] = make_float2(cosf(a), sinf(a));
}

// ---------------- shared 128x128 GEMM mainloop (K=1024, B^T operand) ----------------
// C[m][n] = sum_k A[m][k] * Bt[n][k]
__device__ inline void gemm128_loop(const u16* __restrict__ A, const u16* __restrict__ Bt,
                                    int m0, int n0, u16* As, u16* Bs, f32x4 acc[4][4]) {
    const int tid  = threadIdx.x;
    const int lane = tid & 63;
    const int wid  = tid >> 6;
    const int wm = (wid >> 1) << 6;
    const int wn = (wid & 1) << 6;
    const int lr = lane & 15;
    const int lk = (lane >> 4) << 3;

#pragma unroll
    for (int mi = 0; mi < 4; mi++)
#pragma unroll
        for (int ni = 0; ni < 4; ni++) acc[mi][ni] = f32x4{0.f, 0.f, 0.f, 0.f};

    for (int k0 = 0; k0 < 1024; k0 += 32) {
        // stage 128x32 A-tile and B-tile; linear LDS, global_load_lds width 16
#pragma unroll
        for (int iss = 0; iss < 2; ++iss) {
            int idx = iss * 2048 + tid * 8;
            int row = idx >> 5;
            int col = idx & 31;
            gload_lds16(A  + (int64_t)(m0 + row) * 1024 + (k0 + col), As + idx);
            gload_lds16(Bt + (int64_t)(n0 + row) * 1024 + (k0 + col), Bs + idx);
        }
        __syncthreads();   // drains vmcnt before barrier -> LDS tiles ready
        s16x8 af[4], bf[4];
#pragma unroll
        for (int mi = 0; mi < 4; mi++)
            af[mi] = *(const s16x8*)(As + (wm + mi * 16 + lr) * 32 + lk);
#pragma unroll
        for (int ni = 0; ni < 4; ni++)
            bf[ni] = *(const s16x8*)(Bs + (wn + ni * 16 + lr) * 32 + lk);
#pragma unroll
        for (int mi = 0; mi < 4; mi++)
#pragma unroll
            for (int ni = 0; ni < 4; ni++)
                acc[mi][ni] = mfma16(af[mi], bf[ni], acc[mi][ni]);
        __syncthreads();   // all waves done reading before next stage overwrites
    }
}

// ---------------- QKV projection GEMM: M=4096, N=3072 ----------------
// writes Q/K/V in (B,H,S,D) bf16 layout
__global__ void __launch_bounds__(256)
k_gemm_qkv(const u16* __restrict__ xb, const u16* __restrict__ wqkvb,
           u16* __restrict__ Qb, u16* __restrict__ Kb, u16* __restrict__ Vb) {
    __shared__ u16 As[4096], Bs[4096];
    int m0 = blockIdx.x * 128, n0 = blockIdx.y * 128;
    f32x4 acc[4][4];
    gemm128_loop(xb, wqkvb, m0, n0, As, Bs, acc);
    const int lane = threadIdx.x & 63, wid = threadIdx.x >> 6;
    const int wm = (wid >> 1) << 6, wn = (wid & 1) << 6;
    const int lr = lane & 15, lg = lane >> 4;
#pragma unroll
    for (int mi = 0; mi < 4; mi++) {
#pragma unroll
        for (int ni = 0; ni < 4; ni++) {
            int gn = n0 + wn + ni * 16 + lr;
            int which = gn >> 10;
            int nn = gn & 1023;
            u16* dst = (which == 0) ? Qb : ((which == 1) ? Kb : Vb);
            int h = nn >> 6, d = nn & 63;
#pragma unroll
            for (int r = 0; r < 4; r++) {
                int gm = m0 + wm + mi * 16 + lg * 4 + r;
                int b = gm >> 11, s = gm & 2047;
                dst[(((int64_t)(b * 16 + h) * 2048) + s) * 64 + d] = f2b(acc[mi][ni][r]);
            }
        }
    }
}

// ---------------- RoPE in-place on Q and K ----------------
__global__ void k_rope_apply(u16* __restrict__ Qb, u16* __restrict__ Kb,
                             const float2* __restrict__ tab) {
    const int64_t np = (int64_t)BB * NH * SS * (DKH / 2);  // 2097152 pairs per tensor
    int64_t i0 = (int64_t)blockIdx.x * blockDim.x + threadIdx.x;
    int64_t strd = (int64_t)gridDim.x * blockDim.x;
    for (int64_t t = i0; t < 2 * np; t += strd) {
        u16* buf = (t < np) ? Qb : Kb;
        int64_t e = (t < np) ? t : t - np;
        int j = (int)(e & 31);
        int s = (int)((e >> 5) & 2047);
        int bh = (int)(e >> 16);
        float2 cs = tab[s * 32 + j];
        u16* p = buf + ((int64_t)bh * 2048 + s) * 64 + 2 * j;
        float xe = b2f(p[0]), xo = b2f(p[1]);
        p[0] = f2b(cs.x * xe - cs.y * xo);
        p[1] = f2b(cs.y * xe + cs.x * xo);
    }
}

// ---------------- causal flash attention ----------------
// 4 waves/block; each wave owns 16 q-rows; KV tile = 32 keys
__global__ void __launch_bounds__(256)
k_attn(const u16* __restrict__ Q, const u16* __restrict__ K, const u16* __restrict__ V,
       u16* __restrict__ O) {
    __shared__ u16 Plds[4][512];   // per-wave 16x32 P tile
    const int tid = threadIdx.x;
    const int lane = tid & 63;
    const int wid = tid >> 6;
    const int lr = lane & 15;
    const int lg = lane >> 4;
    const int lk = lg * 8;
    const int bh = blockIdx.x >> 5;                    // 0..31
    const int qb = ((blockIdx.x & 31) << 2) + wid;     // 0..127
    const int q0 = qb << 4;
    const int64_t base = (int64_t)bh * 2048 * 64;
    const u16* Qp = Q + base;
    const u16* Kp = K + base;
    const u16* Vp = V + base;

    // Q fragments: A-operand, rows = q-local, k = d
    s16x8 aq[2];
#pragma unroll
    for (int db = 0; db < 2; ++db)
        aq[db] = *(const s16x8*)(Qp + (q0 + lr) * 64 + db * 32 + lk);

    f32x4 acco[4];
#pragma unroll
    for (int df = 0; df < 4; ++df) acco[df] = f32x4{0.f, 0.f, 0.f, 0.f};
    float mrun[4], lrun[4];
#pragma unroll
    for (int r = 0; r < 4; r++) { mrun[r] = -1e30f; lrun[r] = 0.f; }

    u16* Pw = &Plds[wid][0];
    const int itmax = (q0 + 15) >> 5;
    for (int it = 0; it <= itmax; ++it) {
        const int k0 = it << 5;
        // K fragments: B-operand, col = key-local, k = d  (reads K rows, contiguous)
        s16x8 bk[2][2];
#pragma unroll
        for (int kb = 0; kb < 2; kb++)
#pragma unroll
            for (int db = 0; db < 2; db++)
                bk[kb][db] = *(const s16x8*)(Kp + (k0 + kb * 16 + lr) * 64 + db * 32 + lk);
        f32x4 sc[2] = {f32x4{0.f, 0.f, 0.f, 0.f}, f32x4{0.f, 0.f, 0.f, 0.f}};
#pragma unroll
        for (int kb = 0; kb < 2; kb++)
#pragma unroll
            for (int db = 0; db < 2; db++)
                sc[kb] = mfma16(aq[db], bk[kb][db], sc[kb]);

        // scale + causal mask + online softmax
        float p[2][4], cm[4], rs[4];
#pragma unroll
        for (int r = 0; r < 4; r++) {
            const int qg = q0 + lg * 4 + r;
#pragma unroll
            for (int kb = 0; kb < 2; kb++) {
                const int kg = k0 + kb * 16 + lr;
                float sv = sc[kb][r] * 0.125f;
                p[kb][r] = (kg <= qg) ? sv : -1e30f;
            }
            cm[r] = fmaxf(p[0][r], p[1][r]);
        }
#pragma unroll
        for (int off = 1; off < 16; off <<= 1)
#pragma unroll
            for (int r = 0; r < 4; r++)
                cm[r] = fmaxf(cm[r], __shfl_xor(cm[r], off, 64));
        float mnew[4], alpha[4];
#pragma unroll
        for (int r = 0; r < 4; r++) {
            mnew[r] = fmaxf(mrun[r], cm[r]);
            alpha[r] = __expf(mrun[r] - mnew[r]);
            mrun[r] = mnew[r];
        }
#pragma unroll
        for (int r = 0; r < 4; r++) {
            p[0][r] = __expf(p[0][r] - mnew[r]);
            p[1][r] = __expf(p[1][r] - mnew[r]);
            rs[r] = p[0][r] + p[1][r];
        }
#pragma unroll
        for (int off = 1; off < 16; off <<= 1)
#pragma unroll
            for (int r = 0; r < 4; r++)
                rs[r] += __shfl_xor(rs[r], off, 64);
#pragma unroll
        for (int r = 0; r < 4; r++)
            lrun[r] = lrun[r] * alpha[r] + rs[r];
#pragma unroll
        for (int df = 0; df < 4; ++df)
#pragma unroll
            for (int r = 0; r < 4; r++)
                acco[df][r] *= alpha[r];

        // P (scores layout) -> LDS -> A-fragment layout (per-wave, no block barrier)
#pragma unroll
        for (int kb = 0; kb < 2; kb++)
#pragma unroll
            for (int r = 0; r < 4; r++)
                Pw[(lg * 4 + r) * 32 + kb * 16 + lr] = f2b(p[kb][r]);
        asm volatile("s_waitcnt lgkmcnt(0)" ::: "memory");
        s16x8 ap = *(const s16x8*)(Pw + lr * 32 + lk);

        // V fragments: B-operand, col = d-local, k = key  (strided scalar gathers)
        s16x8 bv[4];
#pragma unroll
        for (int df = 0; df < 4; ++df)
#pragma unroll
            for (int i = 0; i < 8; i++)
                bv[df][i] = (short)Vp[(int64_t)(k0 + lk + i) * 64 + df * 16 + lr];
#pragma unroll
        for (int df = 0; df < 4; ++df)
            acco[df] = mfma16(ap, bv[df], acco[df]);
    }

    const int b = bh >> 4, h = bh & 15;
    float inv[4];
#pragma unroll
    for (int r = 0; r < 4; r++) inv[r] = 1.0f / lrun[r];
#pragma unroll
    for (int df = 0; df < 4; ++df)
#pragma unroll
        for (int r = 0; r < 4; r++) {
            const int s = q0 + lg * 4 + r;
            const int d = df * 16 + lr;
            O[(((int64_t)(b * 2048 + s)) * 16 + h) * 64 + d] = f2b(acco[df][r] * inv[r]);
        }
}

// ---------------- output projection GEMM: M=4096, N=1024, fp32 out ----------------
__global__ void __launch_bounds__(256)
k_gemm_out(const u16* __restrict__ Ob, const u16* __restrict__ wob, float* __restrict__ out) {
    __shared__ u16 As[4096], Bs[4096];
    int m0 = blockIdx.x * 128, n0 = blockIdx.y * 128;
    f32x4 acc[4][4];
    gemm128_loop(Ob, wob, m0, n0, As, Bs, acc);
    const int lane = threadIdx.x & 63, wid = threadIdx.x >> 6;
    const int wm = (wid >> 1) << 6, wn = (wid & 1) << 6;
    const int lr = lane & 15, lg = lane >> 4;
#pragma unroll
    for (int mi = 0; mi < 4; mi++)
#pragma unroll
        for (int ni = 0; ni < 4; ni++) {
            int gn = n0 + wn + ni * 16 + lr;
#pragma unroll
            for (int r = 0; r < 4; r++) {
                int gm = m0 + wm + mi * 16 + lg * 4 + r;
                out[(int64_t)gm * 1024 + gn] = acc[mi][ni][r];
            }
        }
}

extern "C" void kernel_launch(void* const* d_in, const int* in_sizes, int n_in,
                              void* d_out, int out_size, void* d_ws, size_t ws_size,
                              hipStream_t stream) {
    const float* x  = (const float*)d_in[0];
    const int* pos  = (const int*)d_in[1];
    const float* wq = (const float*)d_in[2];
    const float* wk = (const float*)d_in[3];
    const float* wv = (const float*)d_in[4];
    const float* wo = (const float*)d_in[5];
    float* out = (float*)d_out;

    char* w = (char*)d_ws;
    u16* xb    = (u16*)w;    w += (size_t)MROWS * DM * 2;        // 8 MB
    u16* wqkvb = (u16*)w;    w += (size_t)3 * DM * DM * 2;       // 6 MB
    u16* wob   = (u16*)w;    w += (size_t)DM * DM * 2;           // 2 MB
    float2* tab = (float2*)w; w += (size_t)SS * 32 * sizeof(float2); // 512 KB
    u16* Qb = (u16*)w;       w += (size_t)MROWS * DM * 2;        // 8 MB
    u16* Kb = (u16*)w;       w += (size_t)MROWS * DM * 2;        // 8 MB
    u16* Vb = (u16*)w;       w += (size_t)MROWS * DM * 2;        // 8 MB
    u16* Ob = (u16*)w;                                           // 8 MB

    k_prep<<<dim3(1024), dim3(256), 0, stream>>>(x, wq, wk, wv, wo, xb, wqkvb, wob);
    k_rope_table<<<dim3(256), dim3(256), 0, stream>>>(pos, tab);
    k_gemm_qkv<<<dim3(32, 24), dim3(256), 0, stream>>>(xb, wqkvb, Qb, Kb, Vb);
    k_rope_apply<<<dim3(2048), dim3(256), 0, stream>>>(Qb, Kb, tab);
    k_attn<<<dim3(1024), dim3(256), 0, stream>>>(Qb, Kb, Vb, Ob);
    k_gemm_out<<<dim3(32, 8), dim3(256), 0, stream>>>(Ob, wob, out);
}

// Round 2
// 160.647 us; speedup vs baseline: 1.5665x; 1.5665x over previous
//
#include <hip/hip_runtime.h>
#include <hip/hip_bf16.h>

// Problem constants
#define DM    1024
#define NH    16
#define DKH   64
#define BB    2
#define SS    2048
#define MROWS (BB*SS)   // 4096

typedef __attribute__((ext_vector_type(8))) short s16x8;
typedef __attribute__((ext_vector_type(4))) float f32x4;
typedef unsigned short u16;

#if __has_builtin(__builtin_amdgcn_exp2f)
#define EXP2(x) __builtin_amdgcn_exp2f(x)
#else
#define EXP2(x) exp2f(x)
#endif

__device__ inline u16 f2b(float f) {
    __hip_bfloat16 h = __float2bfloat16(f);
    return __builtin_bit_cast(u16, h);
}
__device__ inline float b2f(u16 u) {
    return __bfloat162float(__builtin_bit_cast(__hip_bfloat16, u));
}

__device__ inline f32x4 mfma16(s16x8 a, s16x8 b, f32x4 c) {
    return __builtin_amdgcn_mfma_f32_16x16x32_bf16(a, b, c, 0, 0, 0);
}

__device__ inline void gload_lds16(const u16* g, u16* l) {
    __builtin_amdgcn_global_load_lds((const __attribute__((address_space(1))) void*)g,
                                     (__attribute__((address_space(3))) void*)l, 16, 0, 0);
}

// ---------------- prep: fp32 -> bf16 casts ----------------
__global__ void k_prep(const float* __restrict__ x, const float* __restrict__ wq,
                       const float* __restrict__ wk, const float* __restrict__ wv,
                       const float* __restrict__ wo,
                       u16* __restrict__ xb, u16* __restrict__ wqkvb, u16* __restrict__ wob) {
    int64_t i0 = (int64_t)blockIdx.x * blockDim.x + threadIdx.x;
    int64_t strd = (int64_t)gridDim.x * blockDim.x;
    const float4* x4 = (const float4*)x;
    ushort4* xb4 = (ushort4*)xb;
    for (int64_t t = i0; t < (int64_t)MROWS*DM/4; t += strd) {
        float4 v = x4[t];
        xb4[t] = make_ushort4(f2b(v.x), f2b(v.y), f2b(v.z), f2b(v.w));
    }
    const float4* q4 = (const float4*)wq;
    const float4* k4 = (const float4*)wk;
    const float4* v4 = (const float4*)wv;
    const float4* o4 = (const float4*)wo;
    ushort4* w4  = (ushort4*)wqkvb;
    ushort4* wo4 = (ushort4*)wob;
    const int64_t nw4 = (int64_t)DM*DM/4;   // 262144
    for (int64_t t = i0; t < nw4; t += strd) {
        float4 a = q4[t]; w4[t]         = make_ushort4(f2b(a.x), f2b(a.y), f2b(a.z), f2b(a.w));
        float4 b = k4[t]; w4[nw4 + t]   = make_ushort4(f2b(b.x), f2b(b.y), f2b(b.z), f2b(b.w));
        float4 c = v4[t]; w4[2*nw4 + t] = make_ushort4(f2b(c.x), f2b(c.y), f2b(c.z), f2b(c.w));
        float4 d = o4[t]; wo4[t]        = make_ushort4(f2b(d.x), f2b(d.y), f2b(d.z), f2b(d.w));
    }
}

// ---------------- RoPE cos/sin table ----------------
__global__ void k_rope_table(const int* __restrict__ pos, float2* __restrict__ tab) {
    int i = blockIdx.x * blockDim.x + threadIdx.x;  // SS*32 = 65536
    if (i >= SS * 32) return;
    int s = i >> 5, j = i & 31;
    float p = (float)pos[s];
    float freq = powf(10000.0f, -(float)(2 * j) * (1.0f / 64.0f));
    float a = p * freq;
    tab[i] = make_float2(cosf(a), sinf(a));
}

// ---------------- shared 128x128 GEMM mainloop (K=1024, B^T operand) ----------------
__device__ inline void gemm128_loop(const u16* __restrict__ A, const u16* __restrict__ Bt,
                                    int m0, int n0, u16* As, u16* Bs, f32x4 acc[4][4]) {
    const int tid  = threadIdx.x;
    const int lane = tid & 63;
    const int wid  = tid >> 6;
    const int wm = (wid >> 1) << 6;
    const int wn = (wid & 1) << 6;
    const int lr = lane & 15;
    const int lk = (lane >> 4) << 3;

#pragma unroll
    for (int mi = 0; mi < 4; mi++)
#pragma unroll
        for (int ni = 0; ni < 4; ni++) acc[mi][ni] = f32x4{0.f, 0.f, 0.f, 0.f};

    for (int k0 = 0; k0 < 1024; k0 += 32) {
#pragma unroll
        for (int iss = 0; iss < 2; ++iss) {
            int idx = iss * 2048 + tid * 8;
            int row = idx >> 5;
            int col = idx & 31;
            gload_lds16(A  + (int64_t)(m0 + row) * 1024 + (k0 + col), As + idx);
            gload_lds16(Bt + (int64_t)(n0 + row) * 1024 + (k0 + col), Bs + idx);
        }
        __syncthreads();
        s16x8 af[4], bf[4];
#pragma unroll
        for (int mi = 0; mi < 4; mi++)
            af[mi] = *(const s16x8*)(As + (wm + mi * 16 + lr) * 32 + lk);
#pragma unroll
        for (int ni = 0; ni < 4; ni++)
            bf[ni] = *(const s16x8*)(Bs + (wn + ni * 16 + lr) * 32 + lk);
#pragma unroll
        for (int mi = 0; mi < 4; mi++)
#pragma unroll
            for (int ni = 0; ni < 4; ni++)
                acc[mi][ni] = mfma16(af[mi], bf[ni], acc[mi][ni]);
        __syncthreads();
    }
}

// ---------------- QKV projection GEMM: M=4096, N=3072 ----------------
__global__ void __launch_bounds__(256)
k_gemm_qkv(const u16* __restrict__ xb, const u16* __restrict__ wqkvb,
           u16* __restrict__ Qb, u16* __restrict__ Kb, u16* __restrict__ Vb) {
    __shared__ u16 As[4096], Bs[4096];
    int m0 = blockIdx.x * 128, n0 = blockIdx.y * 128;
    f32x4 acc[4][4];
    gemm128_loop(xb, wqkvb, m0, n0, As, Bs, acc);
    const int lane = threadIdx.x & 63, wid = threadIdx.x >> 6;
    const int wm = (wid >> 1) << 6, wn = (wid & 1) << 6;
    const int lr = lane & 15, lg = lane >> 4;
#pragma unroll
    for (int mi = 0; mi < 4; mi++) {
#pragma unroll
        for (int ni = 0; ni < 4; ni++) {
            int gn = n0 + wn + ni * 16 + lr;
            int which = gn >> 10;
            int nn = gn & 1023;
            u16* dst = (which == 0) ? Qb : ((which == 1) ? Kb : Vb);
            int h = nn >> 6, d = nn & 63;
#pragma unroll
            for (int r = 0; r < 4; r++) {
                int gm = m0 + wm + mi * 16 + lg * 4 + r;
                int b = gm >> 11, s = gm & 2047;
                dst[(((int64_t)(b * 16 + h) * 2048) + s) * 64 + d] = f2b(acc[mi][ni][r]);
            }
        }
    }
}

// ---------------- V transpose: Vb[bh][s][d] -> Vt[bh][d][s] ----------------
__global__ void __launch_bounds__(256)
k_vt(const u16* __restrict__ Vb, u16* __restrict__ Vt) {
    __shared__ u16 tile[64][80];   // pad to 160B rows (16B aligned)
    const int tid = threadIdx.x;
    const int bh = blockIdx.x >> 5;
    const int s0 = (blockIdx.x & 31) << 6;
    const int64_t base = (int64_t)bh * (2048 * 64);
    const int sl = tid >> 2, d0 = (tid & 3) << 4;
    s16x8 v0 = *(const s16x8*)(Vb + base + (int64_t)(s0 + sl) * 64 + d0);
    s16x8 v1 = *(const s16x8*)(Vb + base + (int64_t)(s0 + sl) * 64 + d0 + 8);
    *(s16x8*)&tile[sl][d0] = v0;
    *(s16x8*)&tile[sl][d0 + 8] = v1;
    __syncthreads();
    const int d = tid >> 2, sc0 = (tid & 3) << 4;
    u16 outv[16];
#pragma unroll
    for (int j = 0; j < 16; ++j) outv[j] = tile[sc0 + j][d];
    *(s16x8*)(Vt + base + (int64_t)d * 2048 + s0 + sc0)     = *(s16x8*)&outv[0];
    *(s16x8*)(Vt + base + (int64_t)d * 2048 + s0 + sc0 + 8) = *(s16x8*)&outv[8];
}

// ---------------- RoPE in-place on Q and K; Q gets 0.125*log2(e) folded ----------------
__global__ void k_rope_apply(u16* __restrict__ Qb, u16* __restrict__ Kb,
                             const float2* __restrict__ tab) {
    const float QSC = 0.18033688011112042f;  // (1/8) * log2(e)
    const int64_t np = (int64_t)BB * NH * SS * (DKH / 2);  // 2097152 pairs per tensor
    int64_t i0 = (int64_t)blockIdx.x * blockDim.x + threadIdx.x;
    int64_t strd = (int64_t)gridDim.x * blockDim.x;
    for (int64_t t = i0; t < 2 * np; t += strd) {
        u16* buf = (t < np) ? Qb : Kb;
        float scl = (t < np) ? QSC : 1.0f;
        int64_t e = (t < np) ? t : t - np;
        int j = (int)(e & 31);
        int s = (int)((e >> 5) & 2047);
        int bh = (int)(e >> 16);
        float2 cs = tab[s * 32 + j];
        u16* p = buf + ((int64_t)bh * 2048 + s) * 64 + 2 * j;
        float xe = b2f(p[0]), xo = b2f(p[1]);
        p[0] = f2b((cs.x * xe - cs.y * xo) * scl);
        p[1] = f2b((cs.y * xe + cs.x * xo) * scl);
    }
}

// ---------------- causal flash attention (no-max softmax, exp2 domain) ----------------
// 4 waves/block; each wave owns 32 q-rows; KV tile = 64 keys; per-wave P in LDS (XOR swizzled)
__global__ void __launch_bounds__(256)
k_attn(const u16* __restrict__ Q, const u16* __restrict__ K,
       const u16* __restrict__ Vt, u16* __restrict__ O) {
    __shared__ u16 Plds[4][2048];   // per-wave 32x64 bf16
    const int tid  = threadIdx.x;
    const int lane = tid & 63;
    const int wid  = tid >> 6;
    const int lr = lane & 15;
    const int lg = lane >> 4;
    const int lk = lg * 8;
    const int bh = blockIdx.x >> 4;                     // 0..31
    const int chunk = (blockIdx.x & 15) + (wid << 4);   // 0..63 (balanced across waves)
    const int q0 = chunk << 5;
    const int64_t base = (int64_t)bh * (2048 * 64);
    const u16* Qp = Q  + base;
    const u16* Kp = K  + base;
    const u16* Vp = Vt + base;   // [d][s] layout

    // Q fragments (already scaled by 0.125*log2e in rope)
    s16x8 aq[2][2];
#pragma unroll
    for (int mi = 0; mi < 2; ++mi)
#pragma unroll
        for (int db = 0; db < 2; ++db)
            aq[mi][db] = *(const s16x8*)(Qp + (q0 + mi * 16 + lr) * 64 + db * 32 + lk);

    f32x4 acco[2][4];
    f32x4 accl[2];
#pragma unroll
    for (int mi = 0; mi < 2; ++mi) {
        accl[mi] = f32x4{0.f, 0.f, 0.f, 0.f};
#pragma unroll
        for (int df = 0; df < 4; ++df) acco[mi][df] = f32x4{0.f, 0.f, 0.f, 0.f};
    }
    const s16x8 ones = {(short)0x3F80, (short)0x3F80, (short)0x3F80, (short)0x3F80,
                        (short)0x3F80, (short)0x3F80, (short)0x3F80, (short)0x3F80};
    char* PwB = (char*)(&Plds[wid][0]);
    const int swz = (lr & 7) << 4;

#define P_BLOCK(DIAG)                                                          \
    _Pragma("unroll")                                                          \
    for (int mi = 0; mi < 2; ++mi)                                             \
        _Pragma("unroll")                                                      \
        for (int kb = 0; kb < 4; ++kb)                                         \
            _Pragma("unroll")                                                  \
            for (int r = 0; r < 4; ++r) {                                      \
                int ql = mi * 16 + lg * 4 + r;                                 \
                float s = sc[mi][kb][r];                                       \
                if (DIAG) {                                                    \
                    int kg = k0 + kb * 16 + lr;                                \
                    s = (kg <= q0 + ql) ? s : -3.0e38f;                        \
                }                                                              \
                float p = EXP2(s);                                             \
                int bo = (ql << 7) + ((kb * 16 + lr) << 1);                    \
                *(u16*)(PwB + (bo ^ ((ql & 7) << 4))) = f2b(p);                \
            }

    const int nfull = q0 >> 6;
    for (int t = 0; t <= nfull; ++t) {
        const int k0 = t << 6;
        // V fragments first (used last -> latency hidden under QK^T + softmax)
        s16x8 bv[2][4];
#pragma unroll
        for (int kc = 0; kc < 2; ++kc)
#pragma unroll
            for (int df = 0; df < 4; ++df)
                bv[kc][df] = *(const s16x8*)(Vp + (df * 16 + lr) * 2048 + k0 + kc * 32 + lk);
        // K fragments
        s16x8 bk[4][2];
#pragma unroll
        for (int kb = 0; kb < 4; ++kb)
#pragma unroll
            for (int db = 0; db < 2; ++db)
                bk[kb][db] = *(const s16x8*)(Kp + (k0 + kb * 16 + lr) * 64 + db * 32 + lk);
        // QK^T
        f32x4 sc[2][4];
#pragma unroll
        for (int mi = 0; mi < 2; ++mi)
#pragma unroll
            for (int kb = 0; kb < 4; ++kb) {
                sc[mi][kb] = f32x4{0.f, 0.f, 0.f, 0.f};
#pragma unroll
                for (int db = 0; db < 2; ++db)
                    sc[mi][kb] = mfma16(aq[mi][db], bk[kb][db], sc[mi][kb]);
            }
        // exp2 + P write (mask only on diagonal tile)
        if (t == nfull) { P_BLOCK(1) } else { P_BLOCK(0) }
        asm volatile("s_waitcnt lgkmcnt(0)" ::: "memory");
        // PV + row-sum via all-ones MFMA
#pragma unroll
        for (int mi = 0; mi < 2; ++mi)
#pragma unroll
            for (int kc = 0; kc < 2; ++kc) {
                int ro = ((mi * 16 + lr) << 7) + (kc << 6) + (lg << 4);
                s16x8 ap = *(const s16x8*)(PwB + (ro ^ swz));
#pragma unroll
                for (int df = 0; df < 4; ++df)
                    acco[mi][df] = mfma16(ap, bv[kc][df], acco[mi][df]);
                accl[mi] = mfma16(ap, ones, accl[mi]);
            }
    }
#undef P_BLOCK

    const int b = bh >> 4, h = bh & 15;
#pragma unroll
    for (int mi = 0; mi < 2; ++mi) {
        float inv[4];
#pragma unroll
        for (int r = 0; r < 4; ++r) inv[r] = 1.0f / accl[mi][r];
#pragma unroll
        for (int df = 0; df < 4; ++df)
#pragma unroll
            for (int r = 0; r < 4; ++r) {
                const int s = q0 + mi * 16 + lg * 4 + r;
                const int d = df * 16 + lr;
                O[(((int64_t)(b * 2048 + s)) * 16 + h) * 64 + d] = f2b(acco[mi][df][r] * inv[r]);
            }
    }
}

// ---------------- output projection GEMM: M=4096, N=1024, fp32 out ----------------
__global__ void __launch_bounds__(256)
k_gemm_out(const u16* __restrict__ Ob, const u16* __restrict__ wob, float* __restrict__ out) {
    __shared__ u16 As[4096], Bs[4096];
    int m0 = blockIdx.x * 128, n0 = blockIdx.y * 128;
    f32x4 acc[4][4];
    gemm128_loop(Ob, wob, m0, n0, As, Bs, acc);
    const int lane = threadIdx.x & 63, wid = threadIdx.x >> 6;
    const int wm = (wid >> 1) << 6, wn = (wid & 1) << 6;
    const int lr = lane & 15, lg = lane >> 4;
#pragma unroll
    for (int mi = 0; mi < 4; mi++)
#pragma unroll
        for (int ni = 0; ni < 4; ni++) {
            int gn = n0 + wn + ni * 16 + lr;
#pragma unroll
            for (int r = 0; r < 4; r++) {
                int gm = m0 + wm + mi * 16 + lg * 4 + r;
                out[(int64_t)gm * 1024 + gn] = acc[mi][ni][r];
            }
        }
}

extern "C" void kernel_launch(void* const* d_in, const int* in_sizes, int n_in,
                              void* d_out, int out_size, void* d_ws, size_t ws_size,
                              hipStream_t stream) {
    const float* x  = (const float*)d_in[0];
    const int* pos  = (const int*)d_in[1];
    const float* wq = (const float*)d_in[2];
    const float* wk = (const float*)d_in[3];
    const float* wv = (const float*)d_in[4];
    const float* wo = (const float*)d_in[5];
    float* out = (float*)d_out;

    char* w = (char*)d_ws;
    u16* xb    = (u16*)w;    w += (size_t)MROWS * DM * 2;        // 8 MB
    u16* wqkvb = (u16*)w;    w += (size_t)3 * DM * DM * 2;       // 6 MB
    u16* wob   = (u16*)w;    w += (size_t)DM * DM * 2;           // 2 MB
    float2* tab = (float2*)w; w += (size_t)SS * 32 * sizeof(float2); // 512 KB
    u16* Qb = (u16*)w;       w += (size_t)MROWS * DM * 2;        // 8 MB
    u16* Kb = (u16*)w;       w += (size_t)MROWS * DM * 2;        // 8 MB
    u16* Vb = (u16*)w;       w += (size_t)MROWS * DM * 2;        // 8 MB
    u16* Ob = (u16*)w;                                           // 8 MB
    u16* Vt = xb;   // xb is dead after k_gemm_qkv; reuse for transposed V

    k_prep<<<dim3(1024), dim3(256), 0, stream>>>(x, wq, wk, wv, wo, xb, wqkvb, wob);
    k_rope_table<<<dim3(256), dim3(256), 0, stream>>>(pos, tab);
    k_gemm_qkv<<<dim3(32, 24), dim3(256), 0, stream>>>(xb, wqkvb, Qb, Kb, Vb);
    k_vt<<<dim3(1024), dim3(256), 0, stream>>>(Vb, Vt);
    k_rope_apply<<<dim3(2048), dim3(256), 0, stream>>>(Qb, Kb, tab);
    k_attn<<<dim3(512), dim3(256), 0, stream>>>(Qb, Kb, Vt, Ob);
    k_gemm_out<<<dim3(32, 8), dim3(256), 0, stream>>>(Ob, wob, out);
}